// Round 1
// baseline (10518.288 us; speedup 1.0000x reference)
//
#include <hip/hip_runtime.h>

#define N_NODES   50000
#define N_EDGES   800000
#define N_REL     16
#define N_GRAPHS  64
#define DIM       128     // IN_DIM == HID
#define FC_DIM    256
#define N_CLASSES 16

#define IDENT_PAD 50048                 // ceil64(N_NODES)
#define NBLK_GEMM 13299                 // ceil((800000 + 16*63 + 50048)/64)
#define EPAD_MAX  (NBLK_GEMM * 64)      // 851136
#define POOL_CH   64

// ---- ws layout (bytes) ----
// small ints: bins @ int[0..16], cur @ int[17..33], off_pad @ int[34..51]
#define WS_SMALL   0
#define WS_SRC     256
#define WS_DST     (WS_SRC + EPAD_MAX*4)          // 256 + 3404544 = 3404800
#define WS_AGG1    (WS_DST + EPAD_MAX*4)          // 6809344
#define WS_AGG2    (WS_AGG1 + N_NODES*DIM*4)      // 32409344
#define WS_HGSUM   (WS_AGG2 + N_NODES*DIM*4)      // 58009344
#define WS_CNT     (WS_HGSUM + N_GRAPHS*DIM*4)    // 58042112
#define WS_TOTAL   (WS_CNT + 256)

__device__ __forceinline__ void atomAddF(float* p, float v) {
#if defined(__gfx90a__) || defined(__gfx940__) || defined(__gfx941__) || defined(__gfx942__) || defined(__gfx950__)
    unsafeAtomicAdd(p, v);
#else
    atomicAdd(p, v);
#endif
}

__global__ void k_fill(int* __restrict__ src_s, int* __restrict__ dst_s) {
    int i = blockIdx.x * blockDim.x + threadIdx.x;
    if (i < EPAD_MAX) { src_s[i] = 0; dst_s[i] = -1; }
}

__global__ void k_hist(const int* __restrict__ rel, int* __restrict__ small) {
    int e = blockIdx.x * blockDim.x + threadIdx.x;
    if (e < N_EDGES) atomicAdd(&small[rel[e]], 1);
}

__global__ void k_prefix(int* __restrict__ small) {
    int* bins = small; int* cur = small + 17; int* off = small + 34;
    off[0] = 0;
    for (int r = 0; r < 16; ++r) off[r+1] = off[r] + ((bins[r] + 63) & ~63);
    off[17] = off[16] + IDENT_PAD;
    for (int r = 0; r < 17; ++r) cur[r] = off[r];
}

__global__ void k_scatter(const int* __restrict__ src, const int* __restrict__ dst,
                          const int* __restrict__ rel, int* __restrict__ small,
                          int* __restrict__ src_s, int* __restrict__ dst_s) {
    int i = blockIdx.x * blockDim.x + threadIdx.x;
    int* cur = small + 17; const int* off = small + 34;
    if (i < N_EDGES) {
        int r = rel[i];
        int p = atomicAdd(&cur[r], 1);
        src_s[p] = src[i]; dst_s[p] = dst[i];
    } else if (i < N_EDGES + N_NODES) {
        int v = i - N_EDGES;
        int p = off[16] + v;
        src_s[p] = v; dst_s[p] = v;
    }
}

__global__ void k_init_agg(float* __restrict__ agg, const float* __restrict__ bias) {
    int i = blockIdx.x * blockDim.x + threadIdx.x;   // over N_NODES*32 float4
    if (i < N_NODES * 32) {
        int f4 = i & 31;
        ((float4*)agg)[i] = ((const float4*)bias)[f4];
    }
}

// One block = 64 edges of a single relation segment.
// msg[64,128] = gather(x)[64,128] @ W[r][128,128]; atomic-scatter rows to agg[dst].
__global__ __launch_bounds__(256) void k_edge_gemm(
    const float* __restrict__ xin, const int* __restrict__ src_s,
    const int* __restrict__ dst_s, const int* __restrict__ small,
    const float* __restrict__ Wrel, const float* __restrict__ Wself,
    float* __restrict__ agg, int relu_in)
{
    __shared__ float As[64][36];     // 64 edges x 32-k chunk (pad to 36 for align)
    __shared__ float Bs[32][132];    // 32 k x 128 out (pad 4)
    __shared__ int sSrc[64], sDst[64];
    __shared__ int sRel;

    const int* off = small + 34;
    int tid = threadIdx.x;
    int e0  = blockIdx.x * 64;

    if (tid < 64) { sSrc[tid] = src_s[e0 + tid]; sDst[tid] = dst_s[e0 + tid]; }
    if (tid == 0) {
        int r = 16;
        for (int i = 0; i < 16; ++i)
            if (e0 >= off[i] && e0 < off[i+1]) { r = i; break; }
        sRel = r;
    }
    __syncthreads();

    const float* W = (sRel < 16) ? (Wrel + sRel * (DIM * DIM)) : Wself;

    float acc[4][8];
    #pragma unroll
    for (int i = 0; i < 4; ++i)
        #pragma unroll
        for (int j = 0; j < 8; ++j) acc[i][j] = 0.f;

    int ty = tid >> 4, tx = tid & 15;
    int c0 = tx * 8;
    int ge = tid >> 2, gs = tid & 3;     // A gather: 4 threads per edge row
    int bk = tid >> 3, bf = tid & 7;     // B load: 8 threads per k row
    int srcRow = sSrc[ge];

    for (int k0 = 0; k0 < DIM; k0 += 32) {
        // ---- stage A (gathered x rows, optional relu) ----
        const float4* xr = (const float4*)(xin + srcRow * DIM + k0);
        float4 va = xr[gs];
        float4 vb = xr[gs + 4];
        if (relu_in) {
            va.x = fmaxf(va.x, 0.f); va.y = fmaxf(va.y, 0.f);
            va.z = fmaxf(va.z, 0.f); va.w = fmaxf(va.w, 0.f);
            vb.x = fmaxf(vb.x, 0.f); vb.y = fmaxf(vb.y, 0.f);
            vb.z = fmaxf(vb.z, 0.f); vb.w = fmaxf(vb.w, 0.f);
        }
        *(float4*)&As[ge][gs * 4]      = va;
        *(float4*)&As[ge][gs * 4 + 16] = vb;
        // ---- stage B (W chunk) ----
        const float4* wrow = (const float4*)(W + (k0 + bk) * DIM);
        #pragma unroll
        for (int j = 0; j < 4; ++j)
            *(float4*)&Bs[bk][(bf + 8*j) * 4] = wrow[bf + 8*j];
        __syncthreads();

        #pragma unroll
        for (int k4 = 0; k4 < 32; k4 += 4) {
            float4 a[4];
            #pragma unroll
            for (int i = 0; i < 4; ++i) a[i] = *(const float4*)&As[ty*4 + i][k4];
            #pragma unroll
            for (int kk = 0; kk < 4; ++kk) {
                float4 b0 = *(const float4*)&Bs[k4 + kk][c0];
                float4 b1 = *(const float4*)&Bs[k4 + kk][c0 + 4];
                #pragma unroll
                for (int i = 0; i < 4; ++i) {
                    float av = (kk == 0) ? a[i].x : (kk == 1) ? a[i].y
                             : (kk == 2) ? a[i].z : a[i].w;
                    acc[i][0] += av * b0.x; acc[i][1] += av * b0.y;
                    acc[i][2] += av * b0.z; acc[i][3] += av * b0.w;
                    acc[i][4] += av * b1.x; acc[i][5] += av * b1.y;
                    acc[i][6] += av * b1.z; acc[i][7] += av * b1.w;
                }
            }
        }
        __syncthreads();
    }

    #pragma unroll
    for (int i = 0; i < 4; ++i) {
        int d = sDst[ty*4 + i];
        if (d >= 0) {
            float* ag = agg + d * DIM + c0;
            #pragma unroll
            for (int j = 0; j < 8; ++j) atomAddF(ag + j, acc[i][j]);
        }
    }
}

__global__ void k_pool(const float* __restrict__ agg2, const int* __restrict__ gids,
                       float* __restrict__ hg_sum, int* __restrict__ cnt)
{
    int d  = threadIdx.x;                    // 128
    int n0 = blockIdx.x * POOL_CH;
    int nend = min(n0 + POOL_CH, N_NODES);
    int curg = gids[n0];
    float run = 0.f;
    for (int n = n0; n < nend; ++n) {
        int g = gids[n];
        if (g != curg) { atomAddF(&hg_sum[curg*DIM + d], run); run = 0.f; curg = g; }
        run += fmaxf(agg2[n*DIM + d], 0.f);
    }
    atomAddF(&hg_sum[curg*DIM + d], run);
    if (d == 0) {
        int cg = gids[n0]; int rl = 0;
        for (int n = n0; n < nend; ++n) {
            int g = gids[n];
            if (g != cg) { atomicAdd(&cnt[cg], rl); rl = 0; cg = g; }
            rl++;
        }
        atomicAdd(&cnt[cg], rl);
    }
}

__global__ __launch_bounds__(256) void k_head(
    const float* __restrict__ hg_sum, const int* __restrict__ cnt,
    const float* __restrict__ Wfc, const float* __restrict__ bfc,
    const float* __restrict__ Wc, const float* __restrict__ bc,
    float* __restrict__ out)
{
    int g = blockIdx.x, t = threadIdx.x;
    __shared__ float hgl[DIM];
    __shared__ float fcl[FC_DIM];
    __shared__ float lg[N_CLASSES];
    if (t < DIM) {
        float c = (float)max(cnt[g], 1);
        hgl[t] = hg_sum[g*DIM + t] / c;
    }
    __syncthreads();
    {
        float s = bfc[t];
        #pragma unroll 4
        for (int k = 0; k < DIM; ++k) s += hgl[k] * Wfc[k*FC_DIM + t];
        fcl[t] = fmaxf(s, 0.f);
    }
    __syncthreads();
    if (t < N_CLASSES) {
        float l = bc[t];
        #pragma unroll 4
        for (int k = 0; k < FC_DIM; ++k) l += fcl[k] * Wc[k*N_CLASSES + t];
        lg[t] = l;
    }
    __syncthreads();
    if (t < N_CLASSES) {
        float m = lg[0];
        #pragma unroll
        for (int c = 1; c < N_CLASSES; ++c) m = fmaxf(m, lg[c]);
        float s = 0.f;
        #pragma unroll
        for (int c = 0; c < N_CLASSES; ++c) s += expf(lg[c] - m);
        out[g*N_CLASSES + t] = expf(lg[t] - m) / s;
    }
}

extern "C" void kernel_launch(void* const* d_in, const int* in_sizes, int n_in,
                              void* d_out, int out_size, void* d_ws, size_t ws_size,
                              hipStream_t stream)
{
    const float* h   = (const float*)d_in[0];
    const int*   src = (const int*)d_in[1];
    const int*   dst = (const int*)d_in[2];
    const int*   rel = (const int*)d_in[3];
    const int*   gid = (const int*)d_in[4];
    const float* W1  = (const float*)d_in[5];
    const float* Ws1 = (const float*)d_in[6];
    const float* b1  = (const float*)d_in[7];
    const float* W2  = (const float*)d_in[8];
    const float* Ws2 = (const float*)d_in[9];
    const float* b2  = (const float*)d_in[10];
    const float* Wfc = (const float*)d_in[11];
    const float* bfc = (const float*)d_in[12];
    const float* Wc  = (const float*)d_in[13];
    const float* bc  = (const float*)d_in[14];
    float* out = (float*)d_out;

    char* ws = (char*)d_ws;
    int*   small = (int*)(ws + WS_SMALL);
    int*   src_s = (int*)(ws + WS_SRC);
    int*   dst_s = (int*)(ws + WS_DST);
    float* agg1  = (float*)(ws + WS_AGG1);
    float* agg2  = (float*)(ws + WS_AGG2);
    float* hgsum = (float*)(ws + WS_HGSUM);
    int*   cnt   = (int*)(ws + WS_CNT);

    hipMemsetAsync(small, 0, 256, stream);
    hipMemsetAsync(hgsum, 0, N_GRAPHS*DIM*4 + 256, stream);

    k_fill<<<(EPAD_MAX + 255)/256, 256, 0, stream>>>(src_s, dst_s);
    k_hist<<<(N_EDGES + 255)/256, 256, 0, stream>>>(rel, small);
    k_prefix<<<1, 1, 0, stream>>>(small);
    k_scatter<<<(N_EDGES + N_NODES + 255)/256, 256, 0, stream>>>(src, dst, rel, small, src_s, dst_s);

    k_init_agg<<<(N_NODES*32 + 255)/256, 256, 0, stream>>>(agg1, b1);
    k_edge_gemm<<<NBLK_GEMM, 256, 0, stream>>>(h, src_s, dst_s, small, W1, Ws1, agg1, 0);

    k_init_agg<<<(N_NODES*32 + 255)/256, 256, 0, stream>>>(agg2, b2);
    k_edge_gemm<<<NBLK_GEMM, 256, 0, stream>>>(agg1, src_s, dst_s, small, W2, Ws2, agg2, 1);

    k_pool<<<(N_NODES + POOL_CH - 1)/POOL_CH, 128, 0, stream>>>(agg2, gid, hgsum, cnt);
    k_head<<<N_GRAPHS, 256, 0, stream>>>(hgsum, cnt, Wfc, bfc, Wc, bc, out);
}

// Round 2
// 545.120 us; speedup vs baseline: 19.2954x; 19.2954x over previous
//
#include <hip/hip_runtime.h>
#include <hip/hip_bf16.h>

#define N_NODES   50000
#define N_PAD     50048                 // ceil64
#define N_EDGES   800000
#define N_REL     16
#define N_GRAPHS  64
#define DIM       128
#define FC_DIM    256
#define N_CLASSES 16

#define NBINS     (N_REL * N_PAD)       // 800768 = 782 * 1024 exactly
#define NBLK_SCAN 782
#define NTILES    782                   // N_PAD / 64
#define POOL_CH   64

// ---- ws layout (bytes, 256-aligned) ----
#define WS_HIST   0                                   // NBINS*4 = 3203072
#define WS_OFFS   3203072                             // (NBINS+1)*4 -> 3203328
#define WS_CUR    6406400                             // NBINS*4
#define WS_PART   9609472                             // 4096
#define WS_SRCS   9613568                             // 800000*4 = 3200000
#define WS_X1     12813568                            // 50048*128*2 = 12812288
#define WS_X2     25625856                            // 12812288
#define WS_AGG2   38438144                            // 50048*128*4 = 25624576
#define WS_WB1    64062720                            // 17*128*128*2 = 557056
#define WS_WB2    64619776                            // 557056
#define WS_HG     65176832                            // 64*128*4 = 32768
#define WS_CNT    65209600                            // 256

typedef __attribute__((ext_vector_type(8))) short bf16x8;
typedef __attribute__((ext_vector_type(4))) float f32x4;

__device__ __forceinline__ void atomAddF(float* p, float v) {
#if defined(__gfx90a__) || defined(__gfx942__) || defined(__gfx950__)
    unsafeAtomicAdd(p, v);
#else
    atomicAdd(p, v);
#endif
}

__device__ __forceinline__ float bf2f(unsigned short u) {
    union { float f; unsigned int i; } x; x.i = ((unsigned int)u) << 16; return x.f;
}
__device__ __forceinline__ unsigned short f2bf(float f) {
    union { float f; unsigned int u; } x; x.f = f;
    unsigned int r = x.u + 0x7fff + ((x.u >> 16) & 1);
    return (unsigned short)(r >> 16);
}

// ---- x1 = bf16(h), zero-padded rows ----
__global__ void k_convX(const float* __restrict__ h, unsigned short* __restrict__ x1) {
    int i = blockIdx.x * blockDim.x + threadIdx.x;      // over N_PAD*DIM
    int v = i >> 7;
    x1[i] = (v < N_NODES) ? f2bf(h[i]) : (unsigned short)0;
}

// ---- Wb[r][n][k] = bf16(W[r][k][n]); r==16 -> Ws ----
__global__ void k_convW(const float* __restrict__ W, const float* __restrict__ Ws,
                        unsigned short* __restrict__ Wb) {
    int id = blockIdx.x * blockDim.x + threadIdx.x;     // 17*16384
    int r = id >> 14, rem = id & 16383;
    int n = rem >> 7, k = rem & 127;
    float v = (r < 16) ? W[r * 16384 + k * 128 + n] : Ws[k * 128 + n];
    Wb[id] = f2bf(v);
}

__global__ void k_histK(const int* __restrict__ dst, const int* __restrict__ rel,
                        int* __restrict__ hist) {
    int e = blockIdx.x * blockDim.x + threadIdx.x;
    if (e < N_EDGES) atomicAdd(&hist[rel[e] * N_PAD + dst[e]], 1);
}

__global__ void k_scanA(const int* __restrict__ hist, int* __restrict__ partials) {
    __shared__ int red[256];
    int b = blockIdx.x, t = threadIdx.x;
    int4 v = ((const int4*)(hist + b * 1024))[t];
    red[t] = v.x + v.y + v.z + v.w;
    __syncthreads();
    for (int o = 128; o > 0; o >>= 1) {
        if (t < o) red[t] += red[t + o];
        __syncthreads();
    }
    if (t == 0) partials[b] = red[0];
}

__global__ void k_scanB(int* __restrict__ partials, int* __restrict__ offs_tail) {
    __shared__ int s1[256], s2[256];
    int t = threadIdx.x;
    int v[4]; int sum = 0;
    #pragma unroll
    for (int i = 0; i < 4; ++i) {
        int j = t * 4 + i;
        v[i] = (j < NBLK_SCAN) ? partials[j] : 0;
        sum += v[i];
    }
    s1[t] = sum; __syncthreads();
    int* cur = s1; int* nxt = s2;
    for (int o = 1; o < 256; o <<= 1) {
        nxt[t] = cur[t] + ((t >= o) ? cur[t - o] : 0);
        __syncthreads();
        int* tmp = cur; cur = nxt; nxt = tmp;
    }
    int run = cur[t] - sum;                      // exclusive of this thread
    #pragma unroll
    for (int i = 0; i < 4; ++i) {
        int j = t * 4 + i;
        if (j < NBLK_SCAN) partials[j] = run;
        run += v[i];
    }
    if (t == 255) offs_tail[0] = cur[255];       // offs[NBINS] = total (800000)
}

__global__ void k_scanC(const int* __restrict__ hist, const int* __restrict__ partials,
                        int* __restrict__ offs) {
    __shared__ int s1[256], s2[256];
    int b = blockIdx.x, t = threadIdx.x;
    int4 v = ((const int4*)(hist + b * 1024))[t];
    int sum = v.x + v.y + v.z + v.w;
    s1[t] = sum; __syncthreads();
    int* cur = s1; int* nxt = s2;
    for (int o = 1; o < 256; o <<= 1) {
        nxt[t] = cur[t] + ((t >= o) ? cur[t - o] : 0);
        __syncthreads();
        int* tmp = cur; cur = nxt; nxt = tmp;
    }
    int base = partials[b] + cur[t] - sum;
    int4 w;
    w.x = base;
    w.y = base + v.x;
    w.z = w.y + v.y;
    w.w = w.z + v.z;
    ((int4*)(offs + b * 1024))[t] = w;
}

__global__ void k_scatterK(const int* __restrict__ src, const int* __restrict__ dst,
                           const int* __restrict__ rel, int* __restrict__ cur,
                           int* __restrict__ srcs) {
    int e = blockIdx.x * blockDim.x + threadIdx.x;
    if (e < N_EDGES) {
        int key = rel[e] * N_PAD + dst[e];
        int pos = atomicAdd(&cur[key], 1);
        srcs[pos] = src[e];
    }
}

// ---- fused RGCN layer: per block 64 dsts; loop 17 rels; Q segment-sum + MFMA ----
#define QT_STRIDE 136   // bf16 elems; 272B rows, 16B aligned, <=2-way banks
__global__ __launch_bounds__(256) void k_layer(
    const unsigned short* __restrict__ x, const unsigned short* __restrict__ Wb,
    const int* __restrict__ offs, const int* __restrict__ srcs,
    const float* __restrict__ bias,
    unsigned short* __restrict__ out_bf16, float* __restrict__ out_f32)
{
    __shared__ unsigned short Wt[128 * 128];     // XOR-swizzled 16B chunks
    __shared__ unsigned short Qt[64 * QT_STRIDE];

    int tid = threadIdx.x;
    int v0  = blockIdx.x * 64;
    int g = tid >> 2, s = tid & 3;               // Q-build: 4 threads/dst, 32 feats each
    int wave = tid >> 6, lane = tid & 63;
    int nl = lane & 15, q = lane >> 4;
    int m0 = wave * 16;

    f32x4 acc[8];
    #pragma unroll
    for (int i = 0; i < 8; ++i) acc[i] = (f32x4){0.f, 0.f, 0.f, 0.f};

    for (int r = 0; r < 17; ++r) {
        // ---- stage W[r] transposed+swizzled: Wt[n*128 + ((k8 ^ (n&15))&15)*8] ----
        {
            const unsigned short* wr = Wb + r * 16384;
            #pragma unroll
            for (int it = 0; it < 8; ++it) {
                int c = tid + it * 256;          // 16B chunk id, 0..2047
                int n = c >> 4, k8 = c & 15;
                uint4 val = *(const uint4*)(wr + n * 128 + k8 * 8);
                *(uint4*)(&Wt[n * 128 + ((k8 ^ (n & 15)) & 15) * 8]) = val;
            }
        }
        // ---- build Q tile ----
        if (r == 16) {
            const unsigned short* xr = x + (v0 + g) * 128 + s * 32;
            uint4 a0 = ((const uint4*)xr)[0];
            uint4 a1 = ((const uint4*)xr)[1];
            uint4 a2 = ((const uint4*)xr)[2];
            uint4 a3 = ((const uint4*)xr)[3];
            uint4* qp = (uint4*)(&Qt[g * QT_STRIDE + s * 32]);
            qp[0] = a0; qp[1] = a1; qp[2] = a2; qp[3] = a3;
        } else {
            int key = r * N_PAD + (v0 + g);
            int beg = offs[key], end = offs[key + 1];
            float qa[32];
            #pragma unroll
            for (int i = 0; i < 32; ++i) qa[i] = 0.f;
            for (int e = beg; e < end; ++e) {
                const unsigned short* xr = x + srcs[e] * 128 + s * 32;
                #pragma unroll
                for (int j = 0; j < 4; ++j) {
                    uint4 u = ((const uint4*)xr)[j];
                    qa[j*8+0] += bf2f((unsigned short)(u.x & 0xffff));
                    qa[j*8+1] += bf2f((unsigned short)(u.x >> 16));
                    qa[j*8+2] += bf2f((unsigned short)(u.y & 0xffff));
                    qa[j*8+3] += bf2f((unsigned short)(u.y >> 16));
                    qa[j*8+4] += bf2f((unsigned short)(u.z & 0xffff));
                    qa[j*8+5] += bf2f((unsigned short)(u.z >> 16));
                    qa[j*8+6] += bf2f((unsigned short)(u.w & 0xffff));
                    qa[j*8+7] += bf2f((unsigned short)(u.w >> 16));
                }
            }
            uint4* qp = (uint4*)(&Qt[g * QT_STRIDE + s * 32]);
            #pragma unroll
            for (int j = 0; j < 4; ++j) {
                uint4 w;
                w.x = ((unsigned int)f2bf(qa[j*8+1]) << 16) | f2bf(qa[j*8+0]);
                w.y = ((unsigned int)f2bf(qa[j*8+3]) << 16) | f2bf(qa[j*8+2]);
                w.z = ((unsigned int)f2bf(qa[j*8+5]) << 16) | f2bf(qa[j*8+4]);
                w.w = ((unsigned int)f2bf(qa[j*8+7]) << 16) | f2bf(qa[j*8+6]);
                qp[j] = w;
            }
        }
        __syncthreads();
        // ---- MFMA: wave's 16 rows x 128 cols ----
        #pragma unroll
        for (int kc = 0; kc < 4; ++kc) {
            bf16x8 a = *(const bf16x8*)(&Qt[(m0 + nl) * QT_STRIDE + kc * 32 + q * 8]);
            int sw = (((kc * 4 + q) ^ nl) & 15) * 8;
            #pragma unroll
            for (int nt = 0; nt < 8; ++nt) {
                bf16x8 b = *(const bf16x8*)(&Wt[(nt * 16 + nl) * 128 + sw]);
                acc[nt] = __builtin_amdgcn_mfma_f32_16x16x32_bf16(a, b, acc[nt], 0, 0, 0);
            }
        }
        __syncthreads();
    }

    // ---- epilogue: C layout col=lane&15, row=q*4+reg ----
    #pragma unroll
    for (int nt = 0; nt < 8; ++nt) {
        int col = nt * 16 + nl;
        float bv = bias[col];
        #pragma unroll
        for (int reg = 0; reg < 4; ++reg) {
            int node = v0 + m0 + q * 4 + reg;
            float val = acc[nt][reg] + bv;
            if (out_bf16) out_bf16[node * 128 + col] = f2bf(fmaxf(val, 0.f));
            else          out_f32[node * 128 + col]  = val;
        }
    }
}

__global__ void k_pool(const float* __restrict__ agg2, const int* __restrict__ gids,
                       float* __restrict__ hg_sum, int* __restrict__ cnt)
{
    int d  = threadIdx.x;                    // 128
    int n0 = blockIdx.x * POOL_CH;
    int nend = min(n0 + POOL_CH, N_NODES);
    int curg = gids[n0];
    float run = 0.f;
    for (int n = n0; n < nend; ++n) {
        int g = gids[n];
        if (g != curg) { atomAddF(&hg_sum[curg*DIM + d], run); run = 0.f; curg = g; }
        run += fmaxf(agg2[n*DIM + d], 0.f);
    }
    atomAddF(&hg_sum[curg*DIM + d], run);
    if (d == 0) {
        int cg = gids[n0]; int rl = 0;
        for (int n = n0; n < nend; ++n) {
            int g = gids[n];
            if (g != cg) { atomicAdd(&cnt[cg], rl); rl = 0; cg = g; }
            rl++;
        }
        atomicAdd(&cnt[cg], rl);
    }
}

__global__ __launch_bounds__(256) void k_head(
    const float* __restrict__ hg_sum, const int* __restrict__ cnt,
    const float* __restrict__ Wfc, const float* __restrict__ bfc,
    const float* __restrict__ Wc, const float* __restrict__ bc,
    float* __restrict__ out)
{
    int g = blockIdx.x, t = threadIdx.x;
    __shared__ float hgl[DIM];
    __shared__ float fcl[FC_DIM];
    __shared__ float lg[N_CLASSES];
    if (t < DIM) {
        float c = (float)max(cnt[g], 1);
        hgl[t] = hg_sum[g*DIM + t] / c;
    }
    __syncthreads();
    {
        float sv = bfc[t];
        #pragma unroll 4
        for (int k = 0; k < DIM; ++k) sv += hgl[k] * Wfc[k*FC_DIM + t];
        fcl[t] = fmaxf(sv, 0.f);
    }
    __syncthreads();
    if (t < N_CLASSES) {
        float l = bc[t];
        #pragma unroll 4
        for (int k = 0; k < FC_DIM; ++k) l += fcl[k] * Wc[k*N_CLASSES + t];
        lg[t] = l;
    }
    __syncthreads();
    if (t < N_CLASSES) {
        float m = lg[0];
        #pragma unroll
        for (int c = 1; c < N_CLASSES; ++c) m = fmaxf(m, lg[c]);
        float sden = 0.f;
        #pragma unroll
        for (int c = 0; c < N_CLASSES; ++c) sden += expf(lg[c] - m);
        out[g*N_CLASSES + t] = expf(lg[t] - m) / sden;
    }
}

extern "C" void kernel_launch(void* const* d_in, const int* in_sizes, int n_in,
                              void* d_out, int out_size, void* d_ws, size_t ws_size,
                              hipStream_t stream)
{
    const float* h   = (const float*)d_in[0];
    const int*   src = (const int*)d_in[1];
    const int*   dst = (const int*)d_in[2];
    const int*   rel = (const int*)d_in[3];
    const int*   gid = (const int*)d_in[4];
    const float* W1  = (const float*)d_in[5];
    const float* Ws1 = (const float*)d_in[6];
    const float* b1  = (const float*)d_in[7];
    const float* W2  = (const float*)d_in[8];
    const float* Ws2 = (const float*)d_in[9];
    const float* b2  = (const float*)d_in[10];
    const float* Wfc = (const float*)d_in[11];
    const float* bfc = (const float*)d_in[12];
    const float* Wc  = (const float*)d_in[13];
    const float* bc  = (const float*)d_in[14];
    float* out = (float*)d_out;

    char* ws = (char*)d_ws;
    int*   hist  = (int*)(ws + WS_HIST);
    int*   offs  = (int*)(ws + WS_OFFS);
    int*   cur   = (int*)(ws + WS_CUR);
    int*   part  = (int*)(ws + WS_PART);
    int*   srcs  = (int*)(ws + WS_SRCS);
    unsigned short* x1 = (unsigned short*)(ws + WS_X1);
    unsigned short* x2 = (unsigned short*)(ws + WS_X2);
    float* agg2  = (float*)(ws + WS_AGG2);
    unsigned short* Wb1 = (unsigned short*)(ws + WS_WB1);
    unsigned short* Wb2 = (unsigned short*)(ws + WS_WB2);
    float* hgsum = (float*)(ws + WS_HG);
    int*   cnt   = (int*)(ws + WS_CNT);

    hipMemsetAsync(hist, 0, NBINS * 4, stream);
    hipMemsetAsync(hgsum, 0, N_GRAPHS * DIM * 4, stream);
    hipMemsetAsync(cnt, 0, 256, stream);

    k_convX<<<(N_PAD * DIM) / 256, 256, 0, stream>>>(h, x1);
    k_convW<<<(17 * 16384) / 256, 256, 0, stream>>>(W1, Ws1, Wb1);
    k_convW<<<(17 * 16384) / 256, 256, 0, stream>>>(W2, Ws2, Wb2);

    k_histK<<<(N_EDGES + 255) / 256, 256, 0, stream>>>(dst, rel, hist);
    k_scanA<<<NBLK_SCAN, 256, 0, stream>>>(hist, part);
    k_scanB<<<1, 256, 0, stream>>>(part, offs + NBINS);
    k_scanC<<<NBLK_SCAN, 256, 0, stream>>>(hist, part, offs);
    hipMemcpyAsync(cur, offs, NBINS * 4, hipMemcpyDeviceToDevice, stream);
    k_scatterK<<<(N_EDGES + 255) / 256, 256, 0, stream>>>(src, dst, rel, cur, srcs);

    k_layer<<<NTILES, 256, 0, stream>>>(x1, Wb1, offs, srcs, b1, x2, nullptr);
    k_layer<<<NTILES, 256, 0, stream>>>(x2, Wb2, offs, srcs, b2, nullptr, agg2);

    k_pool<<<(N_NODES + POOL_CH - 1) / POOL_CH, 128, 0, stream>>>(agg2, gid, hgsum, cnt);
    k_head<<<N_GRAPHS, 256, 0, stream>>>(hgsum, cnt, Wfc, bfc, Wc, bc, out);
}